// Round 2
// baseline (3093.782 us; speedup 1.0000x reference)
//
#include <hip/hip_runtime.h>
#include <math.h>

#define BATCH 8
#define SSIZE 1048576   // 128*128*64
#define KT 16

// ---------------- zero kernel (graph-capture-safe G clear) ----------------
__global__ void zero_kernel(float* __restrict__ p, int n) {
    int i = blockIdx.x * blockDim.x + threadIdx.x;
    if (i < n) p[i] = 0.0f;
}

// =====================================================================
// gram128: G[b] (128x128) computed whole per block; split-K over grid y.
// u(b,i,k) planar: off = b*SSIZE + i*SI + (k>>KL2)*SKH + (k & msk)*1  (SKL==1)
// Per-thread 8x8 complex accumulator; one shared A-tile (A==B); reg-prefetch dbuf.
// =====================================================================
template<int SI_, int KL2_, int SKH_>
__global__ __launch_bounds__(256, 2)
void gram128_kernel(const float* __restrict__ srcR, const float* __restrict__ srcI,
                    float* __restrict__ G, int kPerBlock)
{
    const int b      = blockIdx.x;
    const int kbase0 = blockIdx.y * kPerBlock;
    const int t  = threadIdx.x;
    const int ti = t & 15, tj = t >> 4;

    __shared__ float2 As[2][16][130];   // 130: row = 1040B ≡ 4 banks stagger

    float accr[8][8] = {{0.f}}, acci[8][8] = {{0.f}};

    const size_t boff = (size_t)b * SSIZE;
    const int nT = kPerBlock >> 4;

    // staging lane map: kq = float4 group in k (0..3), r0 = row (0..63), iter m adds 64
    const int kq = t & 3;
    const int r0 = t >> 2;

    float4 pR[2], pI[2];

    #define GADDR(ii, k) (boff + (size_t)(ii) * SI_ + \
        (size_t)((k) >> KL2_) * SKH_ + (size_t)((k) & ((1 << KL2_) - 1)))

    // prologue: tile 0
    {
        const int kb = kbase0;
        #pragma unroll
        for (int m = 0; m < 2; m++) {
            const int ii = r0 + 64 * m;
            const size_t off = GADDR(ii, kb + kq * 4);
            pR[m] = *(const float4*)(srcR + off);
            pI[m] = *(const float4*)(srcI + off);
        }
        #pragma unroll
        for (int m = 0; m < 2; m++) {
            const int ii = r0 + 64 * m;
            As[0][kq * 4 + 0][ii] = make_float2(pR[m].x, pI[m].x);
            As[0][kq * 4 + 1][ii] = make_float2(pR[m].y, pI[m].y);
            As[0][kq * 4 + 2][ii] = make_float2(pR[m].z, pI[m].z);
            As[0][kq * 4 + 3][ii] = make_float2(pR[m].w, pI[m].w);
        }
    }
    __syncthreads();

    for (int kt = 0; kt < nT; kt++) {
        const int cur = kt & 1, nxt = cur ^ 1;
        const bool have_next = (kt + 1 < nT);
        if (have_next) {
            const int kb = kbase0 + (kt + 1) * KT;
            #pragma unroll
            for (int m = 0; m < 2; m++) {
                const int ii = r0 + 64 * m;
                const size_t off = GADDR(ii, kb + kq * 4);
                pR[m] = *(const float4*)(srcR + off);
                pI[m] = *(const float4*)(srcI + off);
            }
        }
        // compute tile kt: per kk, 8 float4 LDS reads, 64 complex MACs
        #pragma unroll
        for (int kk = 0; kk < KT; kk++) {
            float4 a4[4], b4[4];
            #pragma unroll
            for (int r = 0; r < 4; r++) a4[r] = *(const float4*)&As[cur][kk][ti * 2 + 32 * r];
            #pragma unroll
            for (int c = 0; c < 4; c++) b4[c] = *(const float4*)&As[cur][kk][tj * 2 + 32 * c];
            #pragma unroll
            for (int r = 0; r < 8; r++) {
                const float ax = (r & 1) ? a4[r >> 1].z : a4[r >> 1].x;
                const float ay = (r & 1) ? a4[r >> 1].w : a4[r >> 1].y;
                #pragma unroll
                for (int c = 0; c < 8; c++) {
                    const float bx = (c & 1) ? b4[c >> 1].z : b4[c >> 1].x;
                    const float by = (c & 1) ? b4[c >> 1].w : b4[c >> 1].y;
                    accr[r][c] = fmaf(ax,  bx, accr[r][c]);
                    accr[r][c] = fmaf(-ay, by, accr[r][c]);
                    acci[r][c] = fmaf(ax,  by, acci[r][c]);
                    acci[r][c] = fmaf(ay,  bx, acci[r][c]);
                }
            }
        }
        if (have_next) {
            #pragma unroll
            for (int m = 0; m < 2; m++) {
                const int ii = r0 + 64 * m;
                As[nxt][kq * 4 + 0][ii] = make_float2(pR[m].x, pI[m].x);
                As[nxt][kq * 4 + 1][ii] = make_float2(pR[m].y, pI[m].y);
                As[nxt][kq * 4 + 2][ii] = make_float2(pR[m].z, pI[m].z);
                As[nxt][kq * 4 + 3][ii] = make_float2(pR[m].w, pI[m].w);
            }
        }
        __syncthreads();
    }
    #undef GADDR

    float* Gb = G + (size_t)b * 128 * 128 * 2;
    #pragma unroll
    for (int r = 0; r < 8; r++) {
        const int i = 2 * ti + (r & 1) + 32 * (r >> 1);
        #pragma unroll
        for (int c = 0; c < 8; c++) {
            const int j = 2 * tj + (c & 1) + 32 * (c >> 1);
            atomicAdd(&Gb[(i * 128 + j) * 2 + 0], accr[r][c]);
            atomicAdd(&Gb[(i * 128 + j) * 2 + 1], acci[r][c]);
        }
    }
}

// =====================================================================
// gram64: mode 2 (d=64). SI=1 (i contiguous), k: (k&127)*64 + (k>>7)*8192.
// Full 64x64 G per block; per-thread 4x4; KT=32; coalesced float4 along i.
// =====================================================================
__global__ __launch_bounds__(256, 2)
void gram64_kernel(const float* __restrict__ srcR, const float* __restrict__ srcI,
                   float* __restrict__ G, int kPerBlock)
{
    const int b      = blockIdx.x;
    const int kbase0 = blockIdx.y * kPerBlock;
    const int t  = threadIdx.x;
    const int ti = t & 15, tj = t >> 4;

    __shared__ float2 As[2][32][66];    // row = 528B ≡ 4 banks stagger

    float accr[4][4] = {{0.f}}, acci[4][4] = {{0.f}};

    const size_t boff = (size_t)b * SSIZE;
    const int nT = kPerBlock >> 5;

    // staging lane map: ii4 = 4*(t&15) (i float4), kk0 = t>>4 (0..15), iter m adds 16
    const int ii4 = (t & 15) * 4;
    const int kk0 = t >> 4;

    float4 pR[2], pI[2];

    #define GADDR64(ii, k) (boff + (size_t)(ii) + \
        (size_t)((k) & 127) * 64 + (size_t)((k) >> 7) * 8192)

    {
        const int kb = kbase0;
        #pragma unroll
        for (int m = 0; m < 2; m++) {
            const int kk = kk0 + 16 * m;
            const size_t off = GADDR64(ii4, kb + kk);
            pR[m] = *(const float4*)(srcR + off);
            pI[m] = *(const float4*)(srcI + off);
        }
        #pragma unroll
        for (int m = 0; m < 2; m++) {
            const int kk = kk0 + 16 * m;
            *(float4*)&As[0][kk][ii4]     = make_float4(pR[m].x, pI[m].x, pR[m].y, pI[m].y);
            *(float4*)&As[0][kk][ii4 + 2] = make_float4(pR[m].z, pI[m].z, pR[m].w, pI[m].w);
        }
    }
    __syncthreads();

    for (int kt = 0; kt < nT; kt++) {
        const int cur = kt & 1, nxt = cur ^ 1;
        const bool have_next = (kt + 1 < nT);
        if (have_next) {
            const int kb = kbase0 + (kt + 1) * 32;
            #pragma unroll
            for (int m = 0; m < 2; m++) {
                const int kk = kk0 + 16 * m;
                const size_t off = GADDR64(ii4, kb + kk);
                pR[m] = *(const float4*)(srcR + off);
                pI[m] = *(const float4*)(srcI + off);
            }
        }
        #pragma unroll
        for (int kk = 0; kk < 32; kk++) {
            float4 a4[2], b4[2];
            #pragma unroll
            for (int r = 0; r < 2; r++) a4[r] = *(const float4*)&As[cur][kk][ti * 2 + 32 * r];
            #pragma unroll
            for (int c = 0; c < 2; c++) b4[c] = *(const float4*)&As[cur][kk][tj * 2 + 32 * c];
            #pragma unroll
            for (int r = 0; r < 4; r++) {
                const float ax = (r & 1) ? a4[r >> 1].z : a4[r >> 1].x;
                const float ay = (r & 1) ? a4[r >> 1].w : a4[r >> 1].y;
                #pragma unroll
                for (int c = 0; c < 4; c++) {
                    const float bx = (c & 1) ? b4[c >> 1].z : b4[c >> 1].x;
                    const float by = (c & 1) ? b4[c >> 1].w : b4[c >> 1].y;
                    accr[r][c] = fmaf(ax,  bx, accr[r][c]);
                    accr[r][c] = fmaf(-ay, by, accr[r][c]);
                    acci[r][c] = fmaf(ax,  by, acci[r][c]);
                    acci[r][c] = fmaf(ay,  bx, acci[r][c]);
                }
            }
        }
        if (have_next) {
            #pragma unroll
            for (int m = 0; m < 2; m++) {
                const int kk = kk0 + 16 * m;
                *(float4*)&As[nxt][kk][ii4]     = make_float4(pR[m].x, pI[m].x, pR[m].y, pI[m].y);
                *(float4*)&As[nxt][kk][ii4 + 2] = make_float4(pR[m].z, pI[m].z, pR[m].w, pI[m].w);
            }
        }
        __syncthreads();
    }
    #undef GADDR64

    float* Gb = G + (size_t)b * 64 * 64 * 2;
    #pragma unroll
    for (int r = 0; r < 4; r++) {
        const int i = 2 * ti + (r & 1) + 32 * (r >> 1);
        #pragma unroll
        for (int c = 0; c < 4; c++) {
            const int j = 2 * tj + (c & 1) + 32 * (c >> 1);
            atomicAdd(&Gb[(i * 64 + j) * 2 + 0], accr[r][c]);
            atomicAdd(&Gb[(i * 64 + j) * 2 + 1], acci[r][c]);
        }
    }
}

// ---------------- score/softmax/phase -> routing matrix M ----------------
__global__ __launch_bounds__(128)
void score_kernel(const float* __restrict__ G,
                  const float* __restrict__ Wre, const float* __restrict__ Wim,
                  const float* __restrict__ log_tau,
                  float2* __restrict__ Mout, int d)
{
    const int b = blockIdx.y;
    const int i = blockIdx.x;
    const int j = threadIdx.x;

    const float2* Gb = (const float2*)G + (size_t)b * d * d;

    float sre = 0.f, sim = 0.f;
    for (int l = 0; l < d; l++) {
        float wr = Wre[i * d + l];
        float wi = Wim[i * d + l];
        float2 g = Gb[l * d + j];
        sre = fmaf(wr, g.x, sre);
        sre = fmaf(-wi, g.y, sre);
        sim = fmaf(wr, g.y, sim);
        sim = fmaf(wi, g.x, sim);
    }

    float mag = sqrtf(sre * sre + sim * sim);
    float tau = fmaxf(expf(log_tau[0]), 1e-8f);
    float scale = tau * sqrtf((float)SSIZE / (float)d);
    float mval = mag / scale;

    __shared__ float red[128];
    red[j] = mval;
    __syncthreads();
    for (int s = d >> 1; s > 0; s >>= 1) {
        if (j < s) red[j] = fmaxf(red[j], red[j + s]);
        __syncthreads();
    }
    float mx = red[0];
    __syncthreads();
    float e = expf(mval - mx);
    red[j] = e;
    __syncthreads();
    for (int s = d >> 1; s > 0; s >>= 1) {
        if (j < s) red[j] += red[j + s];
        __syncthreads();
    }
    float routing = e / red[0];

    float safe = fmaxf(mag, 1e-8f);
    float pre, pim;
    if (mag > 1e-8f) { pre = sre / safe; pim = sim / safe; }
    else             { pre = 1.f;       pim = 0.f; }

    Mout[(size_t)b * d * d + i * d + j] = make_float2(routing * pre, routing * pim);
}

// ---------------- mix: dst(b,i,k) = sum_j M[b,i,j] * u(b,j,k) ----------------
__global__ __launch_bounds__(256)
void mix_kernel(const float* __restrict__ srcR, const float* __restrict__ srcI,
                const float2* __restrict__ M,
                float* __restrict__ dstR, float* __restrict__ dstI,
                int d, int SI, int KL2, int SKL, int SKH)
{
    const int kb0 = blockIdx.x << 6;
    const int it  = blockIdx.y << 6;
    const int b   = blockIdx.z;
    const int msk = (1 << KL2) - 1;

    __shared__ float2 Ms[KT][66];
    __shared__ float2 Us[KT][66];

    const int t  = threadIdx.x;
    const int ti = t & 15, tj = t >> 4;

    float accr[4][4] = {{0}}, acci[4][4] = {{0}};

    const size_t boff = (size_t)b * SSIZE;
    const float2* Mb  = M + (size_t)b * d * d;
    const size_t koff = (size_t)(kb0 >> KL2) * SKH + (size_t)(kb0 & msk) * SKL;

    for (int jb = 0; jb < d; jb += KT) {
        #pragma unroll
        for (int iter = 0; iter < 4; iter++) {
            int l  = iter * 256 + t;
            int jj = l & 15;
            int ii = l >> 4;
            Ms[jj][ii] = Mb[(size_t)(it + ii) * d + (jb + jj)];
        }
        #pragma unroll
        for (int iter = 0; iter < 4; iter++) {
            int l  = iter * 256 + t;
            int kk = l & 63;
            int jj = l >> 6;
            size_t off = boff + (size_t)(jb + jj) * SI + koff + (size_t)kk * SKL;
            Us[jj][kk] = make_float2(srcR[off], srcI[off]);
        }
        __syncthreads();
        #pragma unroll
        for (int jj = 0; jj < KT; jj++) {
            float2 m[4], u[4];
            #pragma unroll
            for (int r = 0; r < 4; r++) m[r] = Ms[jj][ti * 4 + r];
            #pragma unroll
            for (int c = 0; c < 4; c++) u[c] = Us[jj][tj * 4 + c];
            #pragma unroll
            for (int r = 0; r < 4; r++)
                #pragma unroll
                for (int c = 0; c < 4; c++) {
                    accr[r][c] = fmaf(m[r].x,  u[c].x, accr[r][c]);
                    accr[r][c] = fmaf(-m[r].y, u[c].y, accr[r][c]);
                    acci[r][c] = fmaf(m[r].x,  u[c].y, acci[r][c]);
                    acci[r][c] = fmaf(m[r].y,  u[c].x, acci[r][c]);
                }
        }
        __syncthreads();
    }

    #pragma unroll
    for (int r = 0; r < 4; r++)
        #pragma unroll
        for (int c = 0; c < 4; c++) {
            int i = it + ti * 4 + r;
            int kc = tj * 4 + c;
            size_t pos = boff + (size_t)i * SI + koff + (size_t)kc * SKL;
            dstR[pos] = accr[r][c];
            dstI[pos] = acci[r][c];
        }
}

extern "C" void kernel_launch(void* const* d_in, const int* in_sizes, int n_in,
                              void* d_out, int out_size, void* d_ws, size_t ws_size,
                              hipStream_t stream)
{
    const float* xr  = (const float*)d_in[0];
    const float* xi  = (const float*)d_in[1];
    const float* w0r = (const float*)d_in[2];
    const float* w0i = (const float*)d_in[3];
    const float* w1r = (const float*)d_in[4];
    const float* w1i = (const float*)d_in[5];
    const float* w2r = (const float*)d_in[6];
    const float* w2i = (const float*)d_in[7];
    const float* lt  = (const float*)d_in[8];

    float* outR = (float*)d_out;
    float* outI = outR + (size_t)BATCH * SSIZE;

    float*  wsR = (float*)d_ws;
    float*  wsI = wsR + (size_t)BATCH * SSIZE;
    float*  Gf  = wsI + (size_t)BATCH * SSIZE;
    float2* Mf  = (float2*)(Gf + (size_t)BATCH * 128 * 128 * 2);

    const int nG = BATCH * 128 * 128 * 2;

    // ---------------- mode 0: d=128, SI=8192, KL2=13 (k&8191 stride 1), SKH unused
    zero_kernel<<<dim3((nG + 255) / 256), 256, 0, stream>>>(Gf, nG);
    gram128_kernel<8192, 13, 0><<<dim3(BATCH, 64), 256, 0, stream>>>(xr, xi, Gf, 128);
    score_kernel<<<dim3(128, BATCH), 128, 0, stream>>>(Gf, w0r, w0i, lt, Mf, 128);
    mix_kernel<<<dim3(128, 2, BATCH), 256, 0, stream>>>(xr, xi, Mf, outR, outI,
                 128, 8192, 13, 1, 0);

    // ---------------- mode 1: d=128, SI=64, KL2=6, SKH=8192
    zero_kernel<<<dim3((nG + 255) / 256), 256, 0, stream>>>(Gf, nG);
    gram128_kernel<64, 6, 8192><<<dim3(BATCH, 64), 256, 0, stream>>>(outR, outI, Gf, 128);
    score_kernel<<<dim3(128, BATCH), 128, 0, stream>>>(Gf, w1r, w1i, lt, Mf, 128);
    mix_kernel<<<dim3(128, 2, BATCH), 256, 0, stream>>>(outR, outI, Mf, wsR, wsI,
                 128, 64, 6, 1, 8192);

    // ---------------- mode 2: d=64, SI=1, k: (k&127)*64 + (k>>7)*8192
    zero_kernel<<<dim3((nG + 255) / 256), 256, 0, stream>>>(Gf, nG);
    gram64_kernel<<<dim3(BATCH, 64), 256, 0, stream>>>(wsR, wsI, Gf, 256);
    score_kernel<<<dim3(64, BATCH), 64, 0, stream>>>(Gf, w2r, w2i, lt, Mf, 64);
    mix_kernel<<<dim3(256, 1, BATCH), 256, 0, stream>>>(wsR, wsI, Mf, outR, outI,
                 64, 1, 7, 64, 8192);
}